// Round 4
// baseline (13026.715 us; speedup 1.0000x reference)
//
#include <hip/hip_runtime.h>
#include <hip/hip_bf16.h>
#include <cstdio>

typedef unsigned short ushort_t;
typedef unsigned long long u64;
typedef __attribute__((ext_vector_type(4))) float f32x4;
typedef __attribute__((ext_vector_type(4))) unsigned int u32x4;
typedef __attribute__((ext_vector_type(8))) __bf16 bf16x8;
typedef __attribute__((ext_vector_type(8))) unsigned short u16x8;
typedef __attribute__((ext_vector_type(4))) unsigned short u16x4;

#define B_  16
#define T_  1024
#define H_  512
#define NG  2048          // 4*H
#define M_  (B_*T_)       // 16384
#define NBLK_DIR 16       // lstm blocks per direction

__device__ inline unsigned short f2bf_rne(float f){
  union { float f; unsigned int u; } v; v.f = f;
  unsigned int u = v.u;
  unsigned int r = (u + 0x7fffu + ((u >> 16) & 1u)) >> 16;
  return (unsigned short)r;
}
__device__ inline float bf2f(unsigned short s){
  union { unsigned int u; float f; } v; v.u = ((unsigned int)s) << 16;
  return v.f;
}
__device__ inline float sigm_f(float x){
  return 1.0f / (1.0f + __expf(-x));
}
__device__ inline float tanh_f(float x){
  // 1 - 2/(e^{2x}+1): robust at +-large (expf->0 or inf)
  return 1.0f - 2.0f / (__expf(2.0f * x) + 1.0f);
}

__global__ void zero_u32(unsigned* __restrict__ p, int n){
  int i = blockIdx.x * blockDim.x + threadIdx.x;
  if (i < n) p[i] = 0u;
}

// ---------------- split f32 -> bf16 hi + bf16 lo ----------------
__global__ void split_f32_bf16(const float* __restrict__ src,
                               ushort_t* __restrict__ hi, ushort_t* __restrict__ lo,
                               int n4){
  int i = blockIdx.x * blockDim.x + threadIdx.x;
  int stride = gridDim.x * blockDim.x;
  for (; i < n4; i += stride){
    f32x4 v = ((const f32x4*)src)[i];
    u16x4 h4, l4;
    #pragma unroll
    for (int j = 0; j < 4; j++){
      unsigned short h = f2bf_rne(v[j]);
      h4[j] = h;
      l4[j] = f2bf_rne(v[j] - bf2f(h));
    }
    ((u16x4*)hi)[i] = h4;
    ((u16x4*)lo)[i] = l4;
  }
}

// ---------------- split-bf16 MFMA GEMM: C = A * B^T + bias ----------------
__global__ __launch_bounds__(256) void gemm_xg(
    const ushort_t* __restrict__ Ahi, const ushort_t* __restrict__ Alo,
    const ushort_t* __restrict__ Bhi0, const ushort_t* __restrict__ Blo0,
    const ushort_t* __restrict__ Bhi1, const ushort_t* __restrict__ Blo1,
    const float* __restrict__ bi0, const float* __restrict__ bh0,
    const float* __restrict__ bi1, const float* __restrict__ bh1,
    float* __restrict__ C0, float* __restrict__ C1,
    int M, int N, int K)
{
  __shared__ ushort_t As[128*32];
  __shared__ ushort_t Bs[128*32];
  const int tid  = threadIdx.x;
  const int wave = tid >> 6, lane = tid & 63;
  const int l15 = lane & 15, l4 = lane >> 4;
  const int wr = wave >> 1, wc = wave & 1;
  const int n0 = blockIdx.x * 128, m0 = blockIdx.y * 128;
  const int dir = blockIdx.z;
  const ushort_t* Bhi = dir ? Bhi1 : Bhi0;
  const ushort_t* Blo = dir ? Blo1 : Blo0;
  const float* bia = dir ? bi1 : bi0;
  const float* bib = dir ? bh1 : bh0;
  float* C = dir ? C1 : C0;

  f32x4 acc[4][4];
  #pragma unroll
  for (int i = 0; i < 4; i++)
    #pragma unroll
    for (int j = 0; j < 4; j++) acc[i][j] = (f32x4){0.f,0.f,0.f,0.f};

  const int e0 = tid, e1 = 256 + tid;
  const int row0 = e0 >> 2, c80 = (e0 & 3) * 8;
  const int row1 = e1 >> 2, c81 = (e1 & 3) * 8;

  for (int seg = 0; seg < 3; ++seg){
    const ushort_t* Ap = (seg == 2) ? Alo : Ahi;
    const ushort_t* Bp = (seg == 1) ? Blo : Bhi;
    for (int kt = 0; kt < K; kt += 32){
      __builtin_amdgcn_global_load_lds(
        (const __attribute__((address_space(1))) unsigned int*)(Ap + (size_t)(m0 + row0) * K + kt + c80),
        (__attribute__((address_space(3))) unsigned int*)(As + e0 * 8), 16, 0, 0);
      __builtin_amdgcn_global_load_lds(
        (const __attribute__((address_space(1))) unsigned int*)(Bp + (size_t)(n0 + row0) * K + kt + c80),
        (__attribute__((address_space(3))) unsigned int*)(Bs + e0 * 8), 16, 0, 0);
      __builtin_amdgcn_global_load_lds(
        (const __attribute__((address_space(1))) unsigned int*)(Ap + (size_t)(m0 + row1) * K + kt + c81),
        (__attribute__((address_space(3))) unsigned int*)(As + e1 * 8), 16, 0, 0);
      __builtin_amdgcn_global_load_lds(
        (const __attribute__((address_space(1))) unsigned int*)(Bp + (size_t)(n0 + row1) * K + kt + c81),
        (__attribute__((address_space(3))) unsigned int*)(Bs + e1 * 8), 16, 0, 0);
      __syncthreads();
      bf16x8 af[4], bfr[4];
      #pragma unroll
      for (int m = 0; m < 4; m++)
        af[m] = *(const bf16x8*)(As + (wr*64 + m*16 + l15) * 32 + l4 * 8);
      #pragma unroll
      for (int n = 0; n < 4; n++)
        bfr[n] = *(const bf16x8*)(Bs + (wc*64 + n*16 + l15) * 32 + l4 * 8);
      #pragma unroll
      for (int m = 0; m < 4; m++)
        #pragma unroll
        for (int n = 0; n < 4; n++)
          acc[m][n] = __builtin_amdgcn_mfma_f32_16x16x32_bf16(af[m], bfr[n], acc[m][n], 0, 0, 0);
      __syncthreads();
    }
  }
  #pragma unroll
  for (int m = 0; m < 4; m++)
    #pragma unroll
    for (int n = 0; n < 4; n++){
      int col = n0 + wc*64 + n*16 + l15;
      float bias = bia[col] + bib[col];
      #pragma unroll
      for (int r = 0; r < 4; r++){
        int row = m0 + wr*64 + m*16 + l4*4 + r;
        C[(size_t)row * N + col] = acc[m][n][r] + bias;
      }
    }
}

// ---------------- persistent bidirectional LSTM layer (tagged-data handshake) ----------------
// 32 blocks x 512 threads. Block = (dir = blk>>4, cb = blk&15), owns h-cols [32*cb, 32*cb+32).
// Wave = (gate = w>>1, colhalf = w&1). W_hh split-bf16 in registers.
// h exchange: per column ONE u64 = (tag<<32) | (bf16hi | bf16lo<<16), agent-scope relaxed.
// The data store IS the publish; consumers poll tags directly. No flags, no counters,
// no fences, no producer-side waits. Double-buffered by step parity; tag = step+1.
__global__ __launch_bounds__(512, 1) void lstm_layer(
    const float* __restrict__ whh_fwd, const float* __restrict__ whh_bwd,
    const float* __restrict__ xg,      // [2][M_][NG], m = b*T + t
    u64* __restrict__ hbuf,            // [2 dir][2 parity][16][512] u64
    float* __restrict__ out_f32,       // [B][T][1024] or null
    ushort_t* __restrict__ out_hi,     // [B][T][1024] or null (split output)
    ushort_t* __restrict__ out_lo)
{
  const int dir = blockIdx.x >> 4;
  const int cb  = blockIdx.x & 15;
  const int tid = threadIdx.x;
  const int wave = tid >> 6, lane = tid & 63;
  const int gate = wave >> 1, ch = wave & 1;
  const int l15 = lane & 15, l4 = lane >> 4;
  const float* whh = dir ? whh_bwd : whh_fwd;
  u64* hb = hbuf + (size_t)dir * 2 * 8192;   // [parity][16][512]

  // LDS h tile in MFMA-fragment order: u32 slot = ((s*4+l4)*16 + row)*4 + jp
  __shared__ ushort_t hfhi[8192];
  __shared__ ushort_t hflo[8192];
  __shared__ float gbuf[4][16][33];

  // --- W_hh fragments (split bf16): wave rows gate*512 + cb*32 + ch*16 + l15 ---
  bf16x8 Whi[16], Wlo[16];
  {
    const int wrow = gate * 512 + cb * 32 + ch * 16 + l15;
    const float* p0 = whh + (size_t)wrow * 512;
    #pragma unroll
    for (int s = 0; s < 16; s++){
      const float* p = p0 + s * 32 + l4 * 8;
      f32x4 va = *(const f32x4*)(p);
      f32x4 vb = *(const f32x4*)(p + 4);
      u16x8 th, tl;
      #pragma unroll
      for (int j = 0; j < 4; j++){
        unsigned short h = f2bf_rne(va[j]);
        th[j] = h; tl[j] = f2bf_rne(va[j] - bf2f(h));
        unsigned short h2 = f2bf_rne(vb[j]);
        th[4+j] = h2; tl[4+j] = f2bf_rne(vb[j] - bf2f(h2));
      }
      Whi[s] = __builtin_bit_cast(bf16x8, th);
      Wlo[s] = __builtin_bit_cast(bf16x8, tl);
    }
  }

  const int eb = tid >> 5, ecl = tid & 31, ecol = cb * 32 + ecl;

  // stage-unit addressing: u32 frag slot = i*512 + tid  (conflict-free LDS writes)
  //   jp = tid&3, row = (tid>>2)&15, tq = tid>>6
  //   src col-pair base = (tq>>2)*32 + (tq&3)*8 + jp*2, + i*64
  const int srow = (tid >> 2) & 15;
  const int tq = tid >> 6;
  const int sbase = srow * 512 + (tq >> 2) * 32 + (tq & 3) * 8 + (tid & 3) * 2;

  // --- init: publish own slice of h_0 (zeros, tag=1) into parity 0 ---
  __hip_atomic_store(&hb[eb * 512 + ecol], (u64)1u << 32, __ATOMIC_RELAXED, __HIP_MEMORY_SCOPE_AGENT);

  float c_state = 0.0f;

  for (int t = 0; t < T_; ++t){
    // A) prefetch xg for this step (latency hides under the tag-poll)
    const int t_eff = dir ? (T_ - 1 - t) : t;
    const float* xgp = xg + ((size_t)dir * M_ + (size_t)eb * T_ + t_eff) * NG + ecol;
    float xi = xgp[0];
    float xf = xgp[512];
    float xgg = xgp[1024];
    float xo = xgp[1536];

    // B) poll+load h_t: 8 units x 2 tagged u64 (the poll IS the data load)
    const unsigned want = (unsigned)(t + 1);
    const u64* src = hb + (size_t)(t & 1) * 8192;
    u64 va[8], vb[8];
    #pragma unroll
    for (int i = 0; i < 8; i++){
      va[i] = __hip_atomic_load(&src[sbase + i * 64],     __ATOMIC_RELAXED, __HIP_MEMORY_SCOPE_AGENT);
      vb[i] = __hip_atomic_load(&src[sbase + i * 64 + 1], __ATOMIC_RELAXED, __HIP_MEMORY_SCOPE_AGENT);
    }
    for (;;){
      unsigned stale = 0;
      #pragma unroll
      for (int i = 0; i < 8; i++){
        if ((unsigned)(va[i] >> 32) != want || (unsigned)(vb[i] >> 32) != want)
          stale |= 1u << i;
      }
      if (!stale) break;
      #pragma unroll
      for (int i = 0; i < 8; i++){
        if (stale & (1u << i)){
          va[i] = __hip_atomic_load(&src[sbase + i * 64],     __ATOMIC_RELAXED, __HIP_MEMORY_SCOPE_AGENT);
          vb[i] = __hip_atomic_load(&src[sbase + i * 64 + 1], __ATOMIC_RELAXED, __HIP_MEMORY_SCOPE_AGENT);
        }
      }
    }
    // unpack into fragment-order LDS (slot-linear: conflict-free)
    #pragma unroll
    for (int i = 0; i < 8; i++){
      unsigned d0 = (unsigned)va[i], d1 = (unsigned)vb[i];
      ((unsigned*)hfhi)[i * 512 + tid] = (d0 & 0xffffu) | (d1 << 16);
      ((unsigned*)hflo)[i * 512 + tid] = (d0 >> 16) | (d1 & 0xffff0000u);
    }
    __syncthreads();

    // C) gates: 3 independent MFMA chains (hi*Whi, hi*Wlo, lo*Whi)
    {
      f32x4 a0 = {0.f,0.f,0.f,0.f}, a1 = a0, a2 = a0;
      #pragma unroll
      for (int s = 0; s < 16; s++){
        bf16x8 ah = *(const bf16x8*)&hfhi[(s * 64 + l4 * 16 + l15) * 8];
        bf16x8 al = *(const bf16x8*)&hflo[(s * 64 + l4 * 16 + l15) * 8];
        a0 = __builtin_amdgcn_mfma_f32_16x16x32_bf16(ah, Whi[s], a0, 0, 0, 0);
        a1 = __builtin_amdgcn_mfma_f32_16x16x32_bf16(ah, Wlo[s], a1, 0, 0, 0);
        a2 = __builtin_amdgcn_mfma_f32_16x16x32_bf16(al, Whi[s], a2, 0, 0, 0);
      }
      f32x4 acc = a0 + a1;
      acc = acc + a2;
      #pragma unroll
      for (int r = 0; r < 4; r++)
        gbuf[gate][l4 * 4 + r][ch * 16 + l15] = acc[r];
    }
    __syncthreads();

    // D) elementwise LSTM cell; the tagged h store is the ONLY publish (fire-and-forget)
    {
      float pi = gbuf[0][eb][ecl] + xi;
      float pf = gbuf[1][eb][ecl] + xf;
      float pg = gbuf[2][eb][ecl] + xgg;
      float po = gbuf[3][eb][ecl] + xo;
      float ig = sigm_f(pi);
      float fg = sigm_f(pf);
      float gg = tanh_f(pg);
      float og = sigm_f(po);
      c_state = fg * c_state + ig * gg;
      float h = og * tanh_f(c_state);
      unsigned short hh = f2bf_rne(h);
      unsigned short hl = f2bf_rne(h - bf2f(hh));
      unsigned pack = (unsigned)hh | ((unsigned)hl << 16);
      u64 v = ((u64)(unsigned)(t + 2) << 32) | (u64)pack;
      __hip_atomic_store(&hb[(size_t)((t + 1) & 1) * 8192 + eb * 512 + ecol], v,
                         __ATOMIC_RELAXED, __HIP_MEMORY_SCOPE_AGENT);
      // output stores (off critical path)
      size_t oidx = ((size_t)eb * T_ + t_eff) * 1024 + dir * 512 + ecol;
      if (out_f32) out_f32[oidx] = h;
      if (out_hi){ out_hi[oidx] = hh; out_lo[oidx] = hl; }
    }
  }
}

// ---------------- attention pooling ----------------
__device__ inline float dot4(f32x4 a, f32x4 b){
  return a[0]*b[0] + a[1]*b[1] + a[2]*b[2] + a[3]*b[3];
}

__global__ __launch_bounds__(256) void attn_pool(
    const float* __restrict__ out1,   // [B][T][1024]
    const float* __restrict__ aw,     // [1024]
    const float* __restrict__ ab,     // [1]
    float* __restrict__ enc)          // [B][1024]
{
  __shared__ float wbuf[1024];
  __shared__ float sc[1024];
  __shared__ float red[16];
  const int b = blockIdx.x;
  const int tid = threadIdx.x;
  const int wave = tid >> 6, lane = tid & 63;
  ((f32x4*)wbuf)[tid] = ((const f32x4*)aw)[tid];
  __syncthreads();
  const float* ob = out1 + (size_t)b * T_ * 1024;
  const float bias = ab[0];

  for (int t = wave; t < T_; t += 4){
    const float* row = ob + (size_t)t * 1024;
    float s = dot4(((const f32x4*)row)[lane],       ((const f32x4*)wbuf)[lane])
            + dot4(((const f32x4*)row)[lane + 64],  ((const f32x4*)wbuf)[lane + 64])
            + dot4(((const f32x4*)row)[lane + 128], ((const f32x4*)wbuf)[lane + 128])
            + dot4(((const f32x4*)row)[lane + 192], ((const f32x4*)wbuf)[lane + 192]);
    #pragma unroll
    for (int o = 32; o > 0; o >>= 1) s += __shfl_xor(s, o, 64);
    if (lane == 0) sc[t] = s + bias;
  }
  __syncthreads();

  float m = -1e30f;
  for (int i = tid; i < 1024; i += 256) m = fmaxf(m, sc[i]);
  #pragma unroll
  for (int o = 32; o > 0; o >>= 1) m = fmaxf(m, __shfl_xor(m, o, 64));
  if (lane == 0) red[wave] = m;
  __syncthreads();
  m = fmaxf(fmaxf(red[0], red[1]), fmaxf(red[2], red[3]));

  float ssum = 0.f;
  for (int i = tid; i < 1024; i += 256){
    float p = __expf(sc[i] - m);
    sc[i] = p;
    ssum += p;
  }
  #pragma unroll
  for (int o = 32; o > 0; o >>= 1) ssum += __shfl_xor(ssum, o, 64);
  if (lane == 0) red[8 + wave] = ssum;
  __syncthreads();
  float inv = 1.0f / (red[8] + red[9] + red[10] + red[11]);

  f32x4 a = {0.f,0.f,0.f,0.f};
  for (int t = 0; t < T_; t++){
    f32x4 v = *(const f32x4*)(ob + (size_t)t * 1024 + tid * 4);
    float p = sc[t];
    a[0] += p * v[0]; a[1] += p * v[1]; a[2] += p * v[2]; a[3] += p * v[3];
  }
  f32x4 r = { a[0]*inv, a[1]*inv, a[2]*inv, a[3]*inv };
  *(f32x4*)(enc + (size_t)b * 1024 + tid * 4) = r;
}

// ---------------- host ----------------
extern "C" void kernel_launch(void* const* d_in, const int* in_sizes, int n_in,
                              void* d_out, int out_size, void* d_ws, size_t ws_size,
                              hipStream_t stream)
{
  const float* x        = (const float*)d_in[0];
  const float* w_ih_l0  = (const float*)d_in[1];
  const float* w_hh_l0  = (const float*)d_in[2];
  const float* b_ih_l0  = (const float*)d_in[3];
  const float* b_hh_l0  = (const float*)d_in[4];
  const float* w_ih_l0r = (const float*)d_in[5];
  const float* w_hh_l0r = (const float*)d_in[6];
  const float* b_ih_l0r = (const float*)d_in[7];
  const float* b_hh_l0r = (const float*)d_in[8];
  const float* w_ih_l1  = (const float*)d_in[9];
  const float* w_hh_l1  = (const float*)d_in[10];
  const float* b_ih_l1  = (const float*)d_in[11];
  const float* b_hh_l1  = (const float*)d_in[12];
  const float* w_ih_l1r = (const float*)d_in[13];
  const float* w_hh_l1r = (const float*)d_in[14];
  const float* b_ih_l1r = (const float*)d_in[15];
  const float* b_hh_l1r = (const float*)d_in[16];
  const float* attn_w   = (const float*)d_in[17];
  const float* attn_b   = (const float*)d_in[18];
  float* enc = (float*)d_out;

  char* ws = (char*)d_ws;
  size_t off = 0;
  auto alloc = [&](size_t bytes) -> void* {
    void* p = ws + off;
    off += (bytes + 255) & ~(size_t)255;
    return p;
  };
  ushort_t* Ahi  = (ushort_t*)alloc((size_t)M_ * 2048 * 2);
  ushort_t* Alo  = (ushort_t*)alloc((size_t)M_ * 2048 * 2);
  ushort_t* Whi0 = (ushort_t*)alloc((size_t)2048 * 2048 * 2);
  ushort_t* Wlo0 = (ushort_t*)alloc((size_t)2048 * 2048 * 2);
  ushort_t* Whi1 = (ushort_t*)alloc((size_t)2048 * 2048 * 2);
  ushort_t* Wlo1 = (ushort_t*)alloc((size_t)2048 * 2048 * 2);
  float*    xg   = (float*)alloc((size_t)2 * M_ * NG * 4);
  float*    outb = (float*)alloc((size_t)M_ * 1024 * 4);
  u64*      hbuf = (u64*)alloc((size_t)2 * 2 * 2 * 8192 * 8);   // [layer][dir][parity][16][512]
  if (off > ws_size){
    fprintf(stderr, "kernel_launch: workspace too small: need %zu have %zu\n", off, ws_size);
    return;
  }

  // zero tagged h buffers every call (tags monotone within a call; replay-deterministic)
  {
    int n = (int)((size_t)2 * 2 * 2 * 8192 * 8 / 4);
    zero_u32<<<(n + 255) / 256, 256, 0, stream>>>((unsigned*)hbuf, n);
  }

  // ---- layer 0 ----
  split_f32_bf16<<<2048, 256, 0, stream>>>(x, Ahi, Alo, M_ * 2048 / 4);
  split_f32_bf16<<<512, 256, 0, stream>>>(w_ih_l0,  Whi0, Wlo0, 2048 * 2048 / 4);
  split_f32_bf16<<<512, 256, 0, stream>>>(w_ih_l0r, Whi1, Wlo1, 2048 * 2048 / 4);
  gemm_xg<<<dim3(16, 128, 2), 256, 0, stream>>>(
      Ahi, Alo, Whi0, Wlo0, Whi1, Wlo1,
      b_ih_l0, b_hh_l0, b_ih_l0r, b_hh_l0r,
      xg, xg + (size_t)M_ * NG, M_, NG, 2048);
  // LSTM layer 0: writes split-bf16 output directly into Ahi/Alo (x splits dead now)
  lstm_layer<<<32, 512, 0, stream>>>(w_hh_l0, w_hh_l0r, xg, hbuf,
                                     nullptr, Ahi, Alo);
  // ---- layer 1 ----
  split_f32_bf16<<<512, 256, 0, stream>>>(w_ih_l1,  Whi0, Wlo0, 2048 * 1024 / 4);
  split_f32_bf16<<<512, 256, 0, stream>>>(w_ih_l1r, Whi1, Wlo1, 2048 * 1024 / 4);
  gemm_xg<<<dim3(16, 128, 2), 256, 0, stream>>>(
      Ahi, Alo, Whi0, Wlo0, Whi1, Wlo1,
      b_ih_l1, b_hh_l1, b_ih_l1r, b_hh_l1r,
      xg, xg + (size_t)M_ * NG, M_, NG, 1024);
  lstm_layer<<<32, 512, 0, stream>>>(w_hh_l1, w_hh_l1r, xg,
                                     hbuf + (size_t)2 * 2 * 8192,
                                     outb, nullptr, nullptr);
  // ---- attention pooling ----
  attn_pool<<<16, 256, 0, stream>>>(outb, attn_w, attn_b, enc);
}

// Round 5
// 10988.787 us; speedup vs baseline: 1.1855x; 1.1855x over previous
//
#include <hip/hip_runtime.h>
#include <hip/hip_bf16.h>
#include <cstdio>

typedef unsigned short ushort_t;
typedef unsigned long long u64;
typedef __attribute__((ext_vector_type(4))) float f32x4;
typedef __attribute__((ext_vector_type(4))) unsigned int u32x4;
typedef __attribute__((ext_vector_type(8))) __bf16 bf16x8;
typedef __attribute__((ext_vector_type(8))) unsigned short u16x8;
typedef __attribute__((ext_vector_type(4))) unsigned short u16x4;

#define B_  16
#define T_  1024
#define H_  512
#define NG  2048          // 4*H
#define M_  (B_*T_)       // 16384
#define NBLK_DIR 16       // lstm blocks per direction
#define FLG_STRIDE 64     // u32s per (dir) flag row (16 used, 256B padded)

__device__ inline unsigned short f2bf_rne(float f){
  union { float f; unsigned int u; } v; v.f = f;
  unsigned int u = v.u;
  unsigned int r = (u + 0x7fffu + ((u >> 16) & 1u)) >> 16;
  return (unsigned short)r;
}
__device__ inline float bf2f(unsigned short s){
  union { unsigned int u; float f; } v; v.u = ((unsigned int)s) << 16;
  return v.f;
}
__device__ inline float sigm_f(float x){
  return 1.0f / (1.0f + __expf(-x));
}
__device__ inline float tanh_f(float x){
  return 1.0f - 2.0f / (__expf(2.0f * x) + 1.0f);
}

__global__ void zero_u32(unsigned* __restrict__ p, int n){
  int i = blockIdx.x * blockDim.x + threadIdx.x;
  if (i < n) p[i] = 0u;
}

// ---------------- split f32 -> bf16 hi + bf16 lo ----------------
__global__ void split_f32_bf16(const float* __restrict__ src,
                               ushort_t* __restrict__ hi, ushort_t* __restrict__ lo,
                               int n4){
  int i = blockIdx.x * blockDim.x + threadIdx.x;
  int stride = gridDim.x * blockDim.x;
  for (; i < n4; i += stride){
    f32x4 v = ((const f32x4*)src)[i];
    u16x4 h4, l4;
    #pragma unroll
    for (int j = 0; j < 4; j++){
      unsigned short h = f2bf_rne(v[j]);
      h4[j] = h;
      l4[j] = f2bf_rne(v[j] - bf2f(h));
    }
    ((u16x4*)hi)[i] = h4;
    ((u16x4*)lo)[i] = l4;
  }
}

// ---------------- split-bf16 MFMA GEMM: C = A * B^T + bias ----------------
__global__ __launch_bounds__(256) void gemm_xg(
    const ushort_t* __restrict__ Ahi, const ushort_t* __restrict__ Alo,
    const ushort_t* __restrict__ Bhi0, const ushort_t* __restrict__ Blo0,
    const ushort_t* __restrict__ Bhi1, const ushort_t* __restrict__ Blo1,
    const float* __restrict__ bi0, const float* __restrict__ bh0,
    const float* __restrict__ bi1, const float* __restrict__ bh1,
    float* __restrict__ C0, float* __restrict__ C1,
    int M, int N, int K)
{
  __shared__ ushort_t As[128*32];
  __shared__ ushort_t Bs[128*32];
  const int tid  = threadIdx.x;
  const int wave = tid >> 6, lane = tid & 63;
  const int l15 = lane & 15, l4 = lane >> 4;
  const int wr = wave >> 1, wc = wave & 1;
  const int n0 = blockIdx.x * 128, m0 = blockIdx.y * 128;
  const int dir = blockIdx.z;
  const ushort_t* Bhi = dir ? Bhi1 : Bhi0;
  const ushort_t* Blo = dir ? Blo1 : Blo0;
  const float* bia = dir ? bi1 : bi0;
  const float* bib = dir ? bh1 : bh0;
  float* C = dir ? C1 : C0;

  f32x4 acc[4][4];
  #pragma unroll
  for (int i = 0; i < 4; i++)
    #pragma unroll
    for (int j = 0; j < 4; j++) acc[i][j] = (f32x4){0.f,0.f,0.f,0.f};

  const int e0 = tid, e1 = 256 + tid;
  const int row0 = e0 >> 2, c80 = (e0 & 3) * 8;
  const int row1 = e1 >> 2, c81 = (e1 & 3) * 8;

  for (int seg = 0; seg < 3; ++seg){
    const ushort_t* Ap = (seg == 2) ? Alo : Ahi;
    const ushort_t* Bp = (seg == 1) ? Blo : Bhi;
    for (int kt = 0; kt < K; kt += 32){
      __builtin_amdgcn_global_load_lds(
        (const __attribute__((address_space(1))) unsigned int*)(Ap + (size_t)(m0 + row0) * K + kt + c80),
        (__attribute__((address_space(3))) unsigned int*)(As + e0 * 8), 16, 0, 0);
      __builtin_amdgcn_global_load_lds(
        (const __attribute__((address_space(1))) unsigned int*)(Bp + (size_t)(n0 + row0) * K + kt + c80),
        (__attribute__((address_space(3))) unsigned int*)(Bs + e0 * 8), 16, 0, 0);
      __builtin_amdgcn_global_load_lds(
        (const __attribute__((address_space(1))) unsigned int*)(Ap + (size_t)(m0 + row1) * K + kt + c81),
        (__attribute__((address_space(3))) unsigned int*)(As + e1 * 8), 16, 0, 0);
      __builtin_amdgcn_global_load_lds(
        (const __attribute__((address_space(1))) unsigned int*)(Bp + (size_t)(n0 + row1) * K + kt + c81),
        (__attribute__((address_space(3))) unsigned int*)(Bs + e1 * 8), 16, 0, 0);
      __syncthreads();
      bf16x8 af[4], bfr[4];
      #pragma unroll
      for (int m = 0; m < 4; m++)
        af[m] = *(const bf16x8*)(As + (wr*64 + m*16 + l15) * 32 + l4 * 8);
      #pragma unroll
      for (int n = 0; n < 4; n++)
        bfr[n] = *(const bf16x8*)(Bs + (wc*64 + n*16 + l15) * 32 + l4 * 8);
      #pragma unroll
      for (int m = 0; m < 4; m++)
        #pragma unroll
        for (int n = 0; n < 4; n++)
          acc[m][n] = __builtin_amdgcn_mfma_f32_16x16x32_bf16(af[m], bfr[n], acc[m][n], 0, 0, 0);
      __syncthreads();
    }
  }
  #pragma unroll
  for (int m = 0; m < 4; m++)
    #pragma unroll
    for (int n = 0; n < 4; n++){
      int col = n0 + wc*64 + n*16 + l15;
      float bias = bia[col] + bib[col];
      #pragma unroll
      for (int r = 0; r < 4; r++){
        int row = m0 + wr*64 + m*16 + l4*4 + r;
        C[(size_t)row * N + col] = acc[m][n][r] + bias;
      }
    }
}

// ---------------- persistent bidirectional LSTM layer ----------------
// 32 blocks x 512 threads. Block = (dir = blk>>4, cb = blk&15), owns h-cols [32*cb, 32*cb+32).
// Exchange protocol (all agent-scope relaxed, LLC):
//   producer: tagged u64 data stores (fire-and-forget) -> monotone flag value store
//             (NO vmcnt ack, NO barrier between: flags may beat data; tags guard).
//   consumer: 16-lane slim poll on one flag line (>= t+1) -> barrier ->
//             ONE bulk tagged sweep, masked retry only for stragglers.
__global__ __launch_bounds__(512, 1) void lstm_layer(
    const float* __restrict__ whh_fwd, const float* __restrict__ whh_bwd,
    const float* __restrict__ xg,      // [2][M_][NG], m = b*T + t
    u64* __restrict__ hbuf,            // [2 dir][2 parity][16][512] u64
    unsigned* __restrict__ flags,      // [2 dir][FLG_STRIDE] u32 (16 used)
    float* __restrict__ out_f32,       // [B][T][1024] or null
    ushort_t* __restrict__ out_hi,     // [B][T][1024] or null (split output)
    ushort_t* __restrict__ out_lo)
{
  const int dir = blockIdx.x >> 4;
  const int cb  = blockIdx.x & 15;
  const int tid = threadIdx.x;
  const int wave = tid >> 6, lane = tid & 63;
  const int gate = wave >> 1, ch = wave & 1;
  const int l15 = lane & 15, l4 = lane >> 4;
  const float* whh = dir ? whh_bwd : whh_fwd;
  u64* hb = hbuf + (size_t)dir * 2 * 8192;          // [parity][16][512]
  unsigned* flg = flags + (size_t)dir * FLG_STRIDE; // 16 u32, one line

  __shared__ ushort_t hfhi[8192];
  __shared__ ushort_t hflo[8192];
  __shared__ float gbuf[4][16][33];

  // --- W_hh fragments (split bf16): wave rows gate*512 + cb*32 + ch*16 + l15 ---
  bf16x8 Whi[16], Wlo[16];
  {
    const int wrow = gate * 512 + cb * 32 + ch * 16 + l15;
    const float* p0 = whh + (size_t)wrow * 512;
    #pragma unroll
    for (int s = 0; s < 16; s++){
      const float* p = p0 + s * 32 + l4 * 8;
      f32x4 va = *(const f32x4*)(p);
      f32x4 vb = *(const f32x4*)(p + 4);
      u16x8 th, tl;
      #pragma unroll
      for (int j = 0; j < 4; j++){
        unsigned short h = f2bf_rne(va[j]);
        th[j] = h; tl[j] = f2bf_rne(va[j] - bf2f(h));
        unsigned short h2 = f2bf_rne(vb[j]);
        th[4+j] = h2; tl[4+j] = f2bf_rne(vb[j] - bf2f(h2));
      }
      Whi[s] = __builtin_bit_cast(bf16x8, th);
      Wlo[s] = __builtin_bit_cast(bf16x8, tl);
    }
  }

  const int eb = tid >> 5, ecl = tid & 31, ecol = cb * 32 + ecl;

  // bulk-sweep addressing: thread's 16 u64s cover all 16 producer blocks
  const int srow = (tid >> 2) & 15;
  const int tq = tid >> 6;
  const int sbase = srow * 512 + (tq >> 2) * 32 + (tq & 3) * 8 + (tid & 3) * 2;

  // --- init: publish own slice of h_0 (zeros, tag=1), then flag=1 (fire-and-forget) ---
  __hip_atomic_store(&hb[eb * 512 + ecol], (u64)1u << 32, __ATOMIC_RELAXED, __HIP_MEMORY_SCOPE_AGENT);
  if (tid == 0)
    __hip_atomic_store(&flg[cb], 1u, __ATOMIC_RELAXED, __HIP_MEMORY_SCOPE_AGENT);

  float c_state = 0.0f;

  for (int t = 0; t < T_; ++t){
    // A) prefetch xg for this step (latency hides under the poll)
    const int t_eff = dir ? (T_ - 1 - t) : t;
    const float* xgp = xg + ((size_t)dir * M_ + (size_t)eb * T_ + t_eff) * NG + ecol;
    float xi = xgp[0];
    float xf = xgp[512];
    float xgg = xgp[1024];
    float xo = xgp[1536];

    // B) slim poll: 16 lanes watch one 64B flag line (monotone values)
    const unsigned want = (unsigned)(t + 1);
    if (tid < NBLK_DIR){
      while (__hip_atomic_load(&flg[tid], __ATOMIC_RELAXED, __HIP_MEMORY_SCOPE_AGENT) < want)
        __builtin_amdgcn_s_sleep(1);
    }
    __syncthreads();

    // C) ONE bulk tagged sweep; masked retry only for flag-beats-data stragglers
    const u64* src = hb + (size_t)(t & 1) * 8192;
    u64 va[8], vb[8];
    #pragma unroll
    for (int i = 0; i < 8; i++){
      va[i] = __hip_atomic_load(&src[sbase + i * 64],     __ATOMIC_RELAXED, __HIP_MEMORY_SCOPE_AGENT);
      vb[i] = __hip_atomic_load(&src[sbase + i * 64 + 1], __ATOMIC_RELAXED, __HIP_MEMORY_SCOPE_AGENT);
    }
    for (;;){
      unsigned stale = 0;
      #pragma unroll
      for (int i = 0; i < 8; i++){
        if ((unsigned)(va[i] >> 32) != want || (unsigned)(vb[i] >> 32) != want)
          stale |= 1u << i;
      }
      if (!stale) break;
      #pragma unroll
      for (int i = 0; i < 8; i++){
        if (stale & (1u << i)){
          va[i] = __hip_atomic_load(&src[sbase + i * 64],     __ATOMIC_RELAXED, __HIP_MEMORY_SCOPE_AGENT);
          vb[i] = __hip_atomic_load(&src[sbase + i * 64 + 1], __ATOMIC_RELAXED, __HIP_MEMORY_SCOPE_AGENT);
        }
      }
    }
    // unpack into fragment-order LDS (slot-linear: conflict-free)
    #pragma unroll
    for (int i = 0; i < 8; i++){
      unsigned d0 = (unsigned)va[i], d1 = (unsigned)vb[i];
      ((unsigned*)hfhi)[i * 512 + tid] = (d0 & 0xffffu) | (d1 << 16);
      ((unsigned*)hflo)[i * 512 + tid] = (d0 >> 16) | (d1 & 0xffff0000u);
    }
    __syncthreads();

    // D) gates: 3 independent MFMA chains
    {
      f32x4 a0 = {0.f,0.f,0.f,0.f}, a1 = a0, a2 = a0;
      #pragma unroll
      for (int s = 0; s < 16; s++){
        bf16x8 ah = *(const bf16x8*)&hfhi[(s * 64 + l4 * 16 + l15) * 8];
        bf16x8 al = *(const bf16x8*)&hflo[(s * 64 + l4 * 16 + l15) * 8];
        a0 = __builtin_amdgcn_mfma_f32_16x16x32_bf16(ah, Whi[s], a0, 0, 0, 0);
        a1 = __builtin_amdgcn_mfma_f32_16x16x32_bf16(ah, Wlo[s], a1, 0, 0, 0);
        a2 = __builtin_amdgcn_mfma_f32_16x16x32_bf16(al, Whi[s], a2, 0, 0, 0);
      }
      f32x4 acc = a0 + a1;
      acc = acc + a2;
      #pragma unroll
      for (int r = 0; r < 4; r++)
        gbuf[gate][l4 * 4 + r][ch * 16 + l15] = acc[r];
    }
    __syncthreads();

    // E) cell + publish: data stores then flag store, all fire-and-forget
    {
      float pi = gbuf[0][eb][ecl] + xi;
      float pf = gbuf[1][eb][ecl] + xf;
      float pg = gbuf[2][eb][ecl] + xgg;
      float po = gbuf[3][eb][ecl] + xo;
      float ig = sigm_f(pi);
      float fg = sigm_f(pf);
      float gg = tanh_f(pg);
      float og = sigm_f(po);
      c_state = fg * c_state + ig * gg;
      float h = og * tanh_f(c_state);
      unsigned short hh = f2bf_rne(h);
      unsigned short hl = f2bf_rne(h - bf2f(hh));
      unsigned pack = (unsigned)hh | ((unsigned)hl << 16);
      u64 v = ((u64)(unsigned)(t + 2) << 32) | (u64)pack;
      __hip_atomic_store(&hb[(size_t)((t + 1) & 1) * 8192 + eb * 512 + ecol], v,
                         __ATOMIC_RELAXED, __HIP_MEMORY_SCOPE_AGENT);
      if (tid == 0)
        __hip_atomic_store(&flg[cb], (unsigned)(t + 2), __ATOMIC_RELAXED, __HIP_MEMORY_SCOPE_AGENT);
      // output stores (off critical path)
      size_t oidx = ((size_t)eb * T_ + t_eff) * 1024 + dir * 512 + ecol;
      if (out_f32) out_f32[oidx] = h;
      if (out_hi){ out_hi[oidx] = hh; out_lo[oidx] = hl; }
    }
  }
}

// ---------------- attention pooling ----------------
__device__ inline float dot4(f32x4 a, f32x4 b){
  return a[0]*b[0] + a[1]*b[1] + a[2]*b[2] + a[3]*b[3];
}

__global__ __launch_bounds__(256) void attn_pool(
    const float* __restrict__ out1,   // [B][T][1024]
    const float* __restrict__ aw,     // [1024]
    const float* __restrict__ ab,     // [1]
    float* __restrict__ enc)          // [B][1024]
{
  __shared__ float wbuf[1024];
  __shared__ float sc[1024];
  __shared__ float red[16];
  const int b = blockIdx.x;
  const int tid = threadIdx.x;
  const int wave = tid >> 6, lane = tid & 63;
  ((f32x4*)wbuf)[tid] = ((const f32x4*)aw)[tid];
  __syncthreads();
  const float* ob = out1 + (size_t)b * T_ * 1024;
  const float bias = ab[0];

  for (int t = wave; t < T_; t += 4){
    const float* row = ob + (size_t)t * 1024;
    float s = dot4(((const f32x4*)row)[lane],       ((const f32x4*)wbuf)[lane])
            + dot4(((const f32x4*)row)[lane + 64],  ((const f32x4*)wbuf)[lane + 64])
            + dot4(((const f32x4*)row)[lane + 128], ((const f32x4*)wbuf)[lane + 128])
            + dot4(((const f32x4*)row)[lane + 192], ((const f32x4*)wbuf)[lane + 192]);
    #pragma unroll
    for (int o = 32; o > 0; o >>= 1) s += __shfl_xor(s, o, 64);
    if (lane == 0) sc[t] = s + bias;
  }
  __syncthreads();

  float m = -1e30f;
  for (int i = tid; i < 1024; i += 256) m = fmaxf(m, sc[i]);
  #pragma unroll
  for (int o = 32; o > 0; o >>= 1) m = fmaxf(m, __shfl_xor(m, o, 64));
  if (lane == 0) red[wave] = m;
  __syncthreads();
  m = fmaxf(fmaxf(red[0], red[1]), fmaxf(red[2], red[3]));

  float ssum = 0.f;
  for (int i = tid; i < 1024; i += 256){
    float p = __expf(sc[i] - m);
    sc[i] = p;
    ssum += p;
  }
  #pragma unroll
  for (int o = 32; o > 0; o >>= 1) ssum += __shfl_xor(ssum, o, 64);
  if (lane == 0) red[8 + wave] = ssum;
  __syncthreads();
  float inv = 1.0f / (red[8] + red[9] + red[10] + red[11]);

  f32x4 a = {0.f,0.f,0.f,0.f};
  for (int t = 0; t < T_; t++){
    f32x4 v = *(const f32x4*)(ob + (size_t)t * 1024 + tid * 4);
    float p = sc[t];
    a[0] += p * v[0]; a[1] += p * v[1]; a[2] += p * v[2]; a[3] += p * v[3];
  }
  f32x4 r = { a[0]*inv, a[1]*inv, a[2]*inv, a[3]*inv };
  *(f32x4*)(enc + (size_t)b * 1024 + tid * 4) = r;
}

// ---------------- host ----------------
extern "C" void kernel_launch(void* const* d_in, const int* in_sizes, int n_in,
                              void* d_out, int out_size, void* d_ws, size_t ws_size,
                              hipStream_t stream)
{
  const float* x        = (const float*)d_in[0];
  const float* w_ih_l0  = (const float*)d_in[1];
  const float* w_hh_l0  = (const float*)d_in[2];
  const float* b_ih_l0  = (const float*)d_in[3];
  const float* b_hh_l0  = (const float*)d_in[4];
  const float* w_ih_l0r = (const float*)d_in[5];
  const float* w_hh_l0r = (const float*)d_in[6];
  const float* b_ih_l0r = (const float*)d_in[7];
  const float* b_hh_l0r = (const float*)d_in[8];
  const float* w_ih_l1  = (const float*)d_in[9];
  const float* w_hh_l1  = (const float*)d_in[10];
  const float* b_ih_l1  = (const float*)d_in[11];
  const float* b_hh_l1  = (const float*)d_in[12];
  const float* w_ih_l1r = (const float*)d_in[13];
  const float* w_hh_l1r = (const float*)d_in[14];
  const float* b_ih_l1r = (const float*)d_in[15];
  const float* b_hh_l1r = (const float*)d_in[16];
  const float* attn_w   = (const float*)d_in[17];
  const float* attn_b   = (const float*)d_in[18];
  float* enc = (float*)d_out;

  char* ws = (char*)d_ws;
  size_t off = 0;
  auto alloc = [&](size_t bytes) -> void* {
    void* p = ws + off;
    off += (bytes + 255) & ~(size_t)255;
    return p;
  };
  ushort_t* Ahi  = (ushort_t*)alloc((size_t)M_ * 2048 * 2);
  ushort_t* Alo  = (ushort_t*)alloc((size_t)M_ * 2048 * 2);
  ushort_t* Whi0 = (ushort_t*)alloc((size_t)2048 * 2048 * 2);
  ushort_t* Wlo0 = (ushort_t*)alloc((size_t)2048 * 2048 * 2);
  ushort_t* Whi1 = (ushort_t*)alloc((size_t)2048 * 2048 * 2);
  ushort_t* Wlo1 = (ushort_t*)alloc((size_t)2048 * 2048 * 2);
  float*    xg   = (float*)alloc((size_t)2 * M_ * NG * 4);
  float*    outb = (float*)alloc((size_t)M_ * 1024 * 4);
  u64*      hbuf = (u64*)alloc((size_t)2 * 2 * 2 * 8192 * 8);   // [layer][dir][parity][16][512]
  unsigned* flags= (unsigned*)alloc((size_t)2 * 2 * FLG_STRIDE * 4); // [layer][dir][..]
  if (off > ws_size){
    fprintf(stderr, "kernel_launch: workspace too small: need %zu have %zu\n", off, ws_size);
    return;
  }

  // zero tagged h buffers + flags every call (replay-deterministic)
  {
    int n = (int)((size_t)2 * 2 * 2 * 8192 * 8 / 4) + 2 * 2 * FLG_STRIDE;
    zero_u32<<<(n + 255) / 256, 256, 0, stream>>>((unsigned*)hbuf, n);
  }

  // ---- layer 0 ----
  split_f32_bf16<<<2048, 256, 0, stream>>>(x, Ahi, Alo, M_ * 2048 / 4);
  split_f32_bf16<<<512, 256, 0, stream>>>(w_ih_l0,  Whi0, Wlo0, 2048 * 2048 / 4);
  split_f32_bf16<<<512, 256, 0, stream>>>(w_ih_l0r, Whi1, Wlo1, 2048 * 2048 / 4);
  gemm_xg<<<dim3(16, 128, 2), 256, 0, stream>>>(
      Ahi, Alo, Whi0, Wlo0, Whi1, Wlo1,
      b_ih_l0, b_hh_l0, b_ih_l0r, b_hh_l0r,
      xg, xg + (size_t)M_ * NG, M_, NG, 2048);
  lstm_layer<<<32, 512, 0, stream>>>(w_hh_l0, w_hh_l0r, xg, hbuf, flags,
                                     nullptr, Ahi, Alo);
  // ---- layer 1 ----
  split_f32_bf16<<<512, 256, 0, stream>>>(w_ih_l1,  Whi0, Wlo0, 2048 * 1024 / 4);
  split_f32_bf16<<<512, 256, 0, stream>>>(w_ih_l1r, Whi1, Wlo1, 2048 * 1024 / 4);
  gemm_xg<<<dim3(16, 128, 2), 256, 0, stream>>>(
      Ahi, Alo, Whi0, Wlo0, Whi1, Wlo1,
      b_ih_l1, b_hh_l1, b_ih_l1r, b_hh_l1r,
      xg, xg + (size_t)M_ * NG, M_, NG, 1024);
  lstm_layer<<<32, 512, 0, stream>>>(w_hh_l1, w_hh_l1r, xg,
                                     hbuf + (size_t)2 * 2 * 8192,
                                     flags + (size_t)2 * FLG_STRIDE,
                                     outb, nullptr, nullptr);
  // ---- attention pooling ----
  attn_pool<<<16, 256, 0, stream>>>(outb, attn_w, attn_b, enc);
}

// Round 7
// 10117.285 us; speedup vs baseline: 1.2876x; 1.0861x over previous
//
#include <hip/hip_runtime.h>
#include <hip/hip_bf16.h>
#include <cstdio>

typedef unsigned short ushort_t;
typedef unsigned long long u64;
typedef __attribute__((ext_vector_type(4))) float f32x4;
typedef __attribute__((ext_vector_type(4))) unsigned int u32x4;
typedef __attribute__((ext_vector_type(8))) __bf16 bf16x8;
typedef __attribute__((ext_vector_type(8))) unsigned short u16x8;
typedef __attribute__((ext_vector_type(4))) unsigned short u16x4;

#define B_  16
#define T_  1024
#define H_  512
#define NG  2048          // 4*H
#define M_  (B_*T_)       // 16384
#define NBLK_DIR 16       // lstm blocks per direction
#define FLG_STRIDE 64     // u32s per (dir) flag row (16 used, 256B padded)

__device__ inline unsigned short f2bf_rne(float f){
  union { float f; unsigned int u; } v; v.f = f;
  unsigned int u = v.u;
  unsigned int r = (u + 0x7fffu + ((u >> 16) & 1u)) >> 16;
  return (unsigned short)r;
}
__device__ inline float bf2f(unsigned short s){
  union { unsigned int u; float f; } v; v.u = ((unsigned int)s) << 16;
  return v.f;
}
__device__ inline float sigm_f(float x){
  return 1.0f / (1.0f + __expf(-x));
}
__device__ inline float tanh_f(float x){
  return 1.0f - 2.0f / (__expf(2.0f * x) + 1.0f);
}

__global__ void zero_u32(unsigned* __restrict__ p, int n){
  int i = blockIdx.x * blockDim.x + threadIdx.x;
  if (i < n) p[i] = 0u;
}

// ---------------- split f32 -> bf16 hi + bf16 lo ----------------
__global__ void split_f32_bf16(const float* __restrict__ src,
                               ushort_t* __restrict__ hi, ushort_t* __restrict__ lo,
                               int n4){
  int i = blockIdx.x * blockDim.x + threadIdx.x;
  int stride = gridDim.x * blockDim.x;
  for (; i < n4; i += stride){
    f32x4 v = ((const f32x4*)src)[i];
    u16x4 h4, l4;
    #pragma unroll
    for (int j = 0; j < 4; j++){
      unsigned short h = f2bf_rne(v[j]);
      h4[j] = h;
      l4[j] = f2bf_rne(v[j] - bf2f(h));
    }
    ((u16x4*)hi)[i] = h4;
    ((u16x4*)lo)[i] = l4;
  }
}

// ---------------- split-bf16 MFMA GEMM: C = A * B^T + bias ----------------
__global__ __launch_bounds__(256) void gemm_xg(
    const ushort_t* __restrict__ Ahi, const ushort_t* __restrict__ Alo,
    const ushort_t* __restrict__ Bhi0, const ushort_t* __restrict__ Blo0,
    const ushort_t* __restrict__ Bhi1, const ushort_t* __restrict__ Blo1,
    const float* __restrict__ bi0, const float* __restrict__ bh0,
    const float* __restrict__ bi1, const float* __restrict__ bh1,
    float* __restrict__ C0, float* __restrict__ C1,
    int M, int N, int K)
{
  __shared__ ushort_t As[128*32];
  __shared__ ushort_t Bs[128*32];
  const int tid  = threadIdx.x;
  const int wave = tid >> 6, lane = tid & 63;
  const int l15 = lane & 15, l4 = lane >> 4;
  const int wr = wave >> 1, wc = wave & 1;
  const int n0 = blockIdx.x * 128, m0 = blockIdx.y * 128;
  const int dir = blockIdx.z;
  const ushort_t* Bhi = dir ? Bhi1 : Bhi0;
  const ushort_t* Blo = dir ? Blo1 : Blo0;
  const float* bia = dir ? bi1 : bi0;
  const float* bib = dir ? bh1 : bh0;
  float* C = dir ? C1 : C0;

  f32x4 acc[4][4];
  #pragma unroll
  for (int i = 0; i < 4; i++)
    #pragma unroll
    for (int j = 0; j < 4; j++) acc[i][j] = (f32x4){0.f,0.f,0.f,0.f};

  const int e0 = tid, e1 = 256 + tid;
  const int row0 = e0 >> 2, c80 = (e0 & 3) * 8;
  const int row1 = e1 >> 2, c81 = (e1 & 3) * 8;

  for (int seg = 0; seg < 3; ++seg){
    const ushort_t* Ap = (seg == 2) ? Alo : Ahi;
    const ushort_t* Bp = (seg == 1) ? Blo : Bhi;
    for (int kt = 0; kt < K; kt += 32){
      __builtin_amdgcn_global_load_lds(
        (const __attribute__((address_space(1))) unsigned int*)(Ap + (size_t)(m0 + row0) * K + kt + c80),
        (__attribute__((address_space(3))) unsigned int*)(As + e0 * 8), 16, 0, 0);
      __builtin_amdgcn_global_load_lds(
        (const __attribute__((address_space(1))) unsigned int*)(Bp + (size_t)(n0 + row0) * K + kt + c80),
        (__attribute__((address_space(3))) unsigned int*)(Bs + e0 * 8), 16, 0, 0);
      __builtin_amdgcn_global_load_lds(
        (const __attribute__((address_space(1))) unsigned int*)(Ap + (size_t)(m0 + row1) * K + kt + c81),
        (__attribute__((address_space(3))) unsigned int*)(As + e1 * 8), 16, 0, 0);
      __builtin_amdgcn_global_load_lds(
        (const __attribute__((address_space(1))) unsigned int*)(Bp + (size_t)(n0 + row1) * K + kt + c81),
        (__attribute__((address_space(3))) unsigned int*)(Bs + e1 * 8), 16, 0, 0);
      __syncthreads();
      bf16x8 af[4], bfr[4];
      #pragma unroll
      for (int m = 0; m < 4; m++)
        af[m] = *(const bf16x8*)(As + (wr*64 + m*16 + l15) * 32 + l4 * 8);
      #pragma unroll
      for (int n = 0; n < 4; n++)
        bfr[n] = *(const bf16x8*)(Bs + (wc*64 + n*16 + l15) * 32 + l4 * 8);
      #pragma unroll
      for (int m = 0; m < 4; m++)
        #pragma unroll
        for (int n = 0; n < 4; n++)
          acc[m][n] = __builtin_amdgcn_mfma_f32_16x16x32_bf16(af[m], bfr[n], acc[m][n], 0, 0, 0);
      __syncthreads();
    }
  }
  #pragma unroll
  for (int m = 0; m < 4; m++)
    #pragma unroll
    for (int n = 0; n < 4; n++){
      int col = n0 + wc*64 + n*16 + l15;
      float bias = bia[col] + bib[col];
      #pragma unroll
      for (int r = 0; r < 4; r++){
        int row = m0 + wr*64 + m*16 + l4*4 + r;
        C[(size_t)row * N + col] = acc[m][n][r] + bias;
      }
    }
}

// ---------------- persistent bidirectional LSTM layer (chunked exchange) ----------------
// 32 blocks x 512 threads. Block = (dir = blk>>4, cb = blk&15), owns h-cols [32*cb,+32).
// hbuf layout: [dir][parity][producer_cb][512] u64 = (tag<<32)|(bf16hi|bf16lo<<16),
// element index within chunk = batch*32 + col_within. Producer stores are contiguous
// (addr = chunk + tid); consumer reads are contiguous 16B-granular within one chunk.
// Fragment LDS is XOR-swizzled (q_phys = q ^ ((q>>4)&7), 16B units) so the col-pair
// scatter writes are bank-conflict-free while ds_read_b128 frag reads stay balanced.
// Sync: slim 16-lane monotone flag poll + per-u64 tag validation with masked retry.
__global__ __launch_bounds__(512, 1) void lstm_layer(
    const float* __restrict__ whh_fwd, const float* __restrict__ whh_bwd,
    const float* __restrict__ xg,      // [2][M_][NG], m = b*T + t
    u64* __restrict__ hbuf,            // [2 dir][2 parity][16][512] u64
    unsigned* __restrict__ flags,      // [2 dir][FLG_STRIDE] u32 (16 used)
    float* __restrict__ out_f32,       // [B][T][1024] or null
    ushort_t* __restrict__ out_hi,     // [B][T][1024] or null (split output)
    ushort_t* __restrict__ out_lo)
{
  const int dir = blockIdx.x >> 4;
  const int cb  = blockIdx.x & 15;
  const int tid = threadIdx.x;
  const int wave = tid >> 6, lane = tid & 63;
  const int gate = wave >> 1, ch = wave & 1;
  const int l15 = lane & 15, l4 = lane >> 4;
  const float* whh = dir ? whh_bwd : whh_fwd;
  u64* hb = hbuf + (size_t)dir * 2 * 8192;          // [parity][16][512]
  unsigned* flg = flags + (size_t)dir * FLG_STRIDE; // 16 u32, one line

  __shared__ ushort_t hfhi[8192];   // 1024 x 16B units, XOR-swizzled fragment order
  __shared__ ushort_t hflo[8192];
  __shared__ float gbuf[4][16][33];

  // --- W_hh fragments (split bf16): wave rows gate*512 + cb*32 + ch*16 + l15 ---
  bf16x8 Whi[16], Wlo[16];
  {
    const int wrow = gate * 512 + cb * 32 + ch * 16 + l15;
    const float* p0 = whh + (size_t)wrow * 512;
    #pragma unroll
    for (int s = 0; s < 16; s++){
      const float* p = p0 + s * 32 + l4 * 8;
      f32x4 va = *(const f32x4*)(p);
      f32x4 vb = *(const f32x4*)(p + 4);
      u16x8 th, tl;
      #pragma unroll
      for (int j = 0; j < 4; j++){
        unsigned short h = f2bf_rne(va[j]);
        th[j] = h; tl[j] = f2bf_rne(va[j] - bf2f(h));
        unsigned short h2 = f2bf_rne(vb[j]);
        th[4+j] = h2; tl[4+j] = f2bf_rne(vb[j] - bf2f(h2));
      }
      Whi[s] = __builtin_bit_cast(bf16x8, th);
      Wlo[s] = __builtin_bit_cast(bf16x8, tl);
    }
  }

  const int eb = tid >> 5, ecl = tid & 31, ecol = cb * 32 + ecl;

  // consumer sweep addressing: thread covers chunk p, col-pair (2a,2a+1), rows rh*8..+7
  const int p  = tid >> 5;
  const int a  = tid & 15;
  const int rh = (tid >> 4) & 1;
  const int qh = p * 4 + (a >> 2);          // 16B-unit group (column block 0..63)
  const int jp = a & 3;                      // u32 slot within 16B unit
  const int swz = qh & 7;                    // XOR swizzle key
  const size_t cbase = (size_t)p * 512 + rh * 256 + 2 * a;

  // --- init: publish own slice of h_0 (zeros, tag=1), then flag=1 (fire-and-forget) ---
  __hip_atomic_store(&hb[cb * 512 + tid], (u64)1u << 32, __ATOMIC_RELAXED, __HIP_MEMORY_SCOPE_AGENT);
  if (tid == 0)
    __hip_atomic_store(&flg[cb], 1u, __ATOMIC_RELAXED, __HIP_MEMORY_SCOPE_AGENT);

  float c_state = 0.0f;

  for (int t = 0; t < T_; ++t){
    // A) prefetch xg for this step (latency hides under the poll)
    const int t_eff = dir ? (T_ - 1 - t) : t;
    const float* xgp = xg + ((size_t)dir * M_ + (size_t)eb * T_ + t_eff) * NG + ecol;
    float xi = xgp[0];
    float xf = xgp[512];
    float xgg = xgp[1024];
    float xo = xgp[1536];

    // B) slim poll: 16 lanes watch one 64B flag line (monotone values)
    const unsigned want = (unsigned)(t + 1);
    if (tid < NBLK_DIR){
      while (__hip_atomic_load(&flg[tid], __ATOMIC_RELAXED, __HIP_MEMORY_SCOPE_AGENT) < want)
        __builtin_amdgcn_s_sleep(1);
    }
    __syncthreads();

    // C) bulk tagged sweep: 16 u64s, contiguous-ish (16B granules within one 4KB chunk)
    const u64* src = hb + (size_t)(t & 1) * 8192 + cbase;
    u64 va[8], vb[8];
    #pragma unroll
    for (int i = 0; i < 8; i++){
      va[i] = __hip_atomic_load(&src[i * 32],     __ATOMIC_RELAXED, __HIP_MEMORY_SCOPE_AGENT);
      vb[i] = __hip_atomic_load(&src[i * 32 + 1], __ATOMIC_RELAXED, __HIP_MEMORY_SCOPE_AGENT);
    }
    for (;;){
      unsigned stale = 0;
      #pragma unroll
      for (int i = 0; i < 8; i++){
        if ((unsigned)(va[i] >> 32) != want || (unsigned)(vb[i] >> 32) != want)
          stale |= 1u << i;
      }
      if (!stale) break;
      #pragma unroll
      for (int i = 0; i < 8; i++){
        if (stale & (1u << i)){
          va[i] = __hip_atomic_load(&src[i * 32],     __ATOMIC_RELAXED, __HIP_MEMORY_SCOPE_AGENT);
          vb[i] = __hip_atomic_load(&src[i * 32 + 1], __ATOMIC_RELAXED, __HIP_MEMORY_SCOPE_AGENT);
        }
      }
    }
    // unpack into XOR-swizzled fragment LDS (conflict-free scatter: banks fully spread)
    #pragma unroll
    for (int i = 0; i < 8; i++){
      unsigned d0 = (unsigned)va[i], d1 = (unsigned)vb[i];
      unsigned hi = (d0 & 0xffffu) | (d1 << 16);
      unsigned lo = (d0 >> 16) | (d1 & 0xffff0000u);
      int row = rh * 8 + i;
      int qp = qh * 16 + (row ^ swz);
      ((unsigned*)hfhi)[qp * 4 + jp] = hi;
      ((unsigned*)hflo)[qp * 4 + jp] = lo;
    }
    __syncthreads();

    // D) gates: 3 independent MFMA chains, frag reads via the same swizzle
    {
      f32x4 a0 = {0.f,0.f,0.f,0.f}, a1 = a0, a2 = a0;
      #pragma unroll
      for (int s = 0; s < 16; s++){
        int qhr = s * 4 + l4;
        int qpr = qhr * 16 + (l15 ^ (qhr & 7));
        bf16x8 ah = *(const bf16x8*)&hfhi[qpr * 8];
        bf16x8 al = *(const bf16x8*)&hflo[qpr * 8];
        a0 = __builtin_amdgcn_mfma_f32_16x16x32_bf16(ah, Whi[s], a0, 0, 0, 0);
        a1 = __builtin_amdgcn_mfma_f32_16x16x32_bf16(ah, Wlo[s], a1, 0, 0, 0);
        a2 = __builtin_amdgcn_mfma_f32_16x16x32_bf16(al, Whi[s], a2, 0, 0, 0);
      }
      f32x4 acc = a0 + a1;
      acc = acc + a2;
      #pragma unroll
      for (int r = 0; r < 4; r++)
        gbuf[gate][l4 * 4 + r][ch * 16 + l15] = acc[r];
    }
    __syncthreads();

    // E) cell + publish: contiguous tagged data stores then flag store, fire-and-forget
    {
      float pi = gbuf[0][eb][ecl] + xi;
      float pf = gbuf[1][eb][ecl] + xf;
      float pg = gbuf[2][eb][ecl] + xgg;
      float po = gbuf[3][eb][ecl] + xo;
      float ig = sigm_f(pi);
      float fg = sigm_f(pf);
      float gg = tanh_f(pg);
      float og = sigm_f(po);
      c_state = fg * c_state + ig * gg;
      float h = og * tanh_f(c_state);
      unsigned short hh = f2bf_rne(h);
      unsigned short hl = f2bf_rne(h - bf2f(hh));
      unsigned pack = (unsigned)hh | ((unsigned)hl << 16);
      u64 v = ((u64)(unsigned)(t + 2) << 32) | (u64)pack;
      __hip_atomic_store(&hb[(size_t)((t + 1) & 1) * 8192 + cb * 512 + tid], v,
                         __ATOMIC_RELAXED, __HIP_MEMORY_SCOPE_AGENT);
      if (tid == 0)
        __hip_atomic_store(&flg[cb], (unsigned)(t + 2), __ATOMIC_RELAXED, __HIP_MEMORY_SCOPE_AGENT);
      // output stores (off critical path)
      size_t oidx = ((size_t)eb * T_ + t_eff) * 1024 + dir * 512 + ecol;
      if (out_f32) out_f32[oidx] = h;
      if (out_hi){ out_hi[oidx] = hh; out_lo[oidx] = hl; }
    }
  }
}

// ---------------- attention pooling ----------------
__device__ inline float dot4(f32x4 a, f32x4 b){
  return a[0]*b[0] + a[1]*b[1] + a[2]*b[2] + a[3]*b[3];
}

__global__ __launch_bounds__(256) void attn_pool(
    const float* __restrict__ out1,   // [B][T][1024]
    const float* __restrict__ aw,     // [1024]
    const float* __restrict__ ab,     // [1]
    float* __restrict__ enc)          // [B][1024]
{
  __shared__ float wbuf[1024];
  __shared__ float sc[1024];
  __shared__ float red[16];
  const int b = blockIdx.x;
  const int tid = threadIdx.x;
  const int wave = tid >> 6, lane = tid & 63;
  ((f32x4*)wbuf)[tid] = ((const f32x4*)aw)[tid];
  __syncthreads();
  const float* ob = out1 + (size_t)b * T_ * 1024;
  const float bias = ab[0];

  for (int t = wave; t < T_; t += 4){
    const float* row = ob + (size_t)t * 1024;
    float s = dot4(((const f32x4*)row)[lane],       ((const f32x4*)wbuf)[lane])
            + dot4(((const f32x4*)row)[lane + 64],  ((const f32x4*)wbuf)[lane + 64])
            + dot4(((const f32x4*)row)[lane + 128], ((const f32x4*)wbuf)[lane + 128])
            + dot4(((const f32x4*)row)[lane + 192], ((const f32x4*)wbuf)[lane + 192]);
    #pragma unroll
    for (int o = 32; o > 0; o >>= 1) s += __shfl_xor(s, o, 64);
    if (lane == 0) sc[t] = s + bias;
  }
  __syncthreads();

  float m = -1e30f;
  for (int i = tid; i < 1024; i += 256) m = fmaxf(m, sc[i]);
  #pragma unroll
  for (int o = 32; o > 0; o >>= 1) m = fmaxf(m, __shfl_xor(m, o, 64));
  if (lane == 0) red[wave] = m;
  __syncthreads();
  m = fmaxf(fmaxf(red[0], red[1]), fmaxf(red[2], red[3]));

  float ssum = 0.f;
  for (int i = tid; i < 1024; i += 256){
    float p = __expf(sc[i] - m);
    sc[i] = p;
    ssum += p;
  }
  #pragma unroll
  for (int o = 32; o > 0; o >>= 1) ssum += __shfl_xor(ssum, o, 64);
  if (lane == 0) red[8 + wave] = ssum;
  __syncthreads();
  float inv = 1.0f / (red[8] + red[9] + red[10] + red[11]);

  f32x4 a = {0.f,0.f,0.f,0.f};
  for (int t = 0; t < T_; t++){
    f32x4 v = *(const f32x4*)(ob + (size_t)t * 1024 + tid * 4);
    float p = sc[t];
    a[0] += p * v[0]; a[1] += p * v[1]; a[2] += p * v[2]; a[3] += p * v[3];
  }
  f32x4 r = { a[0]*inv, a[1]*inv, a[2]*inv, a[3]*inv };
  *(f32x4*)(enc + (size_t)b * 1024 + tid * 4) = r;
}

// ---------------- host ----------------
extern "C" void kernel_launch(void* const* d_in, const int* in_sizes, int n_in,
                              void* d_out, int out_size, void* d_ws, size_t ws_size,
                              hipStream_t stream)
{
  const float* x        = (const float*)d_in[0];
  const float* w_ih_l0  = (const float*)d_in[1];
  const float* w_hh_l0  = (const float*)d_in[2];
  const float* b_ih_l0  = (const float*)d_in[3];
  const float* b_hh_l0  = (const float*)d_in[4];
  const float* w_ih_l0r = (const float*)d_in[5];
  const float* w_hh_l0r = (const float*)d_in[6];
  const float* b_ih_l0r = (const float*)d_in[7];
  const float* b_hh_l0r = (const float*)d_in[8];
  const float* w_ih_l1  = (const float*)d_in[9];
  const float* w_hh_l1  = (const float*)d_in[10];
  const float* b_ih_l1  = (const float*)d_in[11];
  const float* b_hh_l1  = (const float*)d_in[12];
  const float* w_ih_l1r = (const float*)d_in[13];
  const float* w_hh_l1r = (const float*)d_in[14];
  const float* b_ih_l1r = (const float*)d_in[15];
  const float* b_hh_l1r = (const float*)d_in[16];
  const float* attn_w   = (const float*)d_in[17];
  const float* attn_b   = (const float*)d_in[18];
  float* enc = (float*)d_out;

  char* ws = (char*)d_ws;
  size_t off = 0;
  auto alloc = [&](size_t bytes) -> void* {
    void* p = ws + off;
    off += (bytes + 255) & ~(size_t)255;
    return p;
  };
  ushort_t* Ahi  = (ushort_t*)alloc((size_t)M_ * 2048 * 2);
  ushort_t* Alo  = (ushort_t*)alloc((size_t)M_ * 2048 * 2);
  ushort_t* Whi0 = (ushort_t*)alloc((size_t)2048 * 2048 * 2);
  ushort_t* Wlo0 = (ushort_t*)alloc((size_t)2048 * 2048 * 2);
  ushort_t* Whi1 = (ushort_t*)alloc((size_t)2048 * 2048 * 2);
  ushort_t* Wlo1 = (ushort_t*)alloc((size_t)2048 * 2048 * 2);
  float*    xg   = (float*)alloc((size_t)2 * M_ * NG * 4);
  float*    outb = (float*)alloc((size_t)M_ * 1024 * 4);
  u64*      hbuf = (u64*)alloc((size_t)2 * 2 * 2 * 8192 * 8);   // [layer][dir][parity][16][512]
  unsigned* flags= (unsigned*)alloc((size_t)2 * 2 * FLG_STRIDE * 4); // [layer][dir][..]
  if (off > ws_size){
    fprintf(stderr, "kernel_launch: workspace too small: need %zu have %zu\n", off, ws_size);
    return;
  }

  // zero tagged h buffers + flags every call (replay-deterministic)
  {
    int n = (int)((size_t)2 * 2 * 2 * 8192 * 8 / 4) + 2 * 2 * FLG_STRIDE;
    zero_u32<<<(n + 255) / 256, 256, 0, stream>>>((unsigned*)hbuf, n);
  }

  // ---- layer 0 ----
  split_f32_bf16<<<2048, 256, 0, stream>>>(x, Ahi, Alo, M_ * 2048 / 4);
  split_f32_bf16<<<512, 256, 0, stream>>>(w_ih_l0,  Whi0, Wlo0, 2048 * 2048 / 4);
  split_f32_bf16<<<512, 256, 0, stream>>>(w_ih_l0r, Whi1, Wlo1, 2048 * 2048 / 4);
  gemm_xg<<<dim3(16, 128, 2), 256, 0, stream>>>(
      Ahi, Alo, Whi0, Wlo0, Whi1, Wlo1,
      b_ih_l0, b_hh_l0, b_ih_l0r, b_hh_l0r,
      xg, xg + (size_t)M_ * NG, M_, NG, 2048);
  lstm_layer<<<32, 512, 0, stream>>>(w_hh_l0, w_hh_l0r, xg, hbuf, flags,
                                     nullptr, Ahi, Alo);
  // ---- layer 1 ----
  split_f32_bf16<<<512, 256, 0, stream>>>(w_ih_l1,  Whi0, Wlo0, 2048 * 1024 / 4);
  split_f32_bf16<<<512, 256, 0, stream>>>(w_ih_l1r, Whi1, Wlo1, 2048 * 1024 / 4);
  gemm_xg<<<dim3(16, 128, 2), 256, 0, stream>>>(
      Ahi, Alo, Whi0, Wlo0, Whi1, Wlo1,
      b_ih_l1, b_hh_l1, b_ih_l1r, b_hh_l1r,
      xg, xg + (size_t)M_ * NG, M_, NG, 1024);
  lstm_layer<<<32, 512, 0, stream>>>(w_hh_l1, w_hh_l1r, xg,
                                     hbuf + (size_t)2 * 2 * 8192,
                                     flags + (size_t)2 * FLG_STRIDE,
                                     outb, nullptr, nullptr);
  // ---- attention pooling ----
  attn_pool<<<16, 256, 0, stream>>>(outb, attn_w, attn_b, enc);
}